// Round 5
// baseline (103.846 us; speedup 1.0000x reference)
//
#include <hip/hip_runtime.h>

// Chamfer distance via MFMA, B=8, N=M=8192, fp32-accurate bf16 hi/lo split.
// D[i,j] = sq1_i + sq2_j - 2*<p1_i, p2_j> computed as ONE K=16 bf16 dot:
//   slots 0-8 : coords hi/lo  (a=(h,h,l), b=(H,L,H) per coord; -2 folded into b)
//   slots 9,10: a=(1,1)      b=(s2h,s2l)
//   slots 11,12: a=(s1h,s1l) b=(1,1)
// One 32x32x16 MFMA tile serves BOTH dist1 (row-min) and dist2 (col-min).

typedef unsigned int uint;
typedef unsigned short ushort;
typedef __attribute__((ext_vector_type(8))) short short8;
typedef __attribute__((ext_vector_type(16))) float f32x16;

#define B_    8
#define N_    8192
#define M_    8192
#define BN    (B_ * N_)          // 65536
#define SPLITJ 8
#define JCH   (M_ / SPLITJ)      // 1024 cols per block
#define JT    (JCH / 32)         // 32 j-tiles per block
#define RPB   256                // rows per block (4 waves * 64)
#define RBLK  (N_ / RPB)         // 32 row-blocks per batch

__device__ __forceinline__ uint key_of(float f) {
    uint u = __float_as_uint(f);
    return (u & 0x80000000u) ? ~u : (u | 0x80000000u);
}
__device__ __forceinline__ float val_of(uint k) {
    return __uint_as_float((k & 0x80000000u) ? (k & 0x7FFFFFFFu) : ~k);
}
__device__ __forceinline__ ushort f2bf(float f) {   // RNE f32 -> bf16 bits
    uint u = __float_as_uint(f);
    return (ushort)((u + 0x7FFFu + ((u >> 16) & 1u)) >> 16);
}
__device__ __forceinline__ float bf2f(ushort h) {
    return __uint_as_float(((uint)h) << 16);
}

__global__ void init_kernel(uint* __restrict__ enc) {
    int i = blockIdx.x * blockDim.x + threadIdx.x;
    if (i < 2 * BN) enc[i] = 0xFFFFFFFFu;
}

// mode 0: row-side (cloud1), mode 1: col-side (cloud2, coords scaled by -2)
__global__ void prep_kernel(const float* __restrict__ xyz,
                            ushort* __restrict__ vec, int mode) {
    int i = blockIdx.x * blockDim.x + threadIdx.x;
    if (i >= BN) return;
    float x = xyz[3 * i], y = xyz[3 * i + 1], z = xyz[3 * i + 2];
    float s = fmaf(x, x, fmaf(y, y, z * z));
    if (mode) { x *= -2.0f; y *= -2.0f; z *= -2.0f; }
    ushort xh = f2bf(x), xl = f2bf(x - bf2f(xh));
    ushort yh = f2bf(y), yl = f2bf(y - bf2f(yh));
    ushort zh = f2bf(z), zl = f2bf(z - bf2f(zh));
    ushort sh = f2bf(s), sl = f2bf(s - bf2f(sh));
    const ushort one = 0x3F80;
    ushort v[16];
    if (mode == 0) {
        v[0]=xh; v[1]=xh; v[2]=xl;  v[3]=yh; v[4]=yh; v[5]=yl;
        v[6]=zh; v[7]=zh; v[8]=zl;  v[9]=one; v[10]=one; v[11]=sh; v[12]=sl;
        v[13]=0; v[14]=0; v[15]=0;
    } else {
        v[0]=xh; v[1]=xl; v[2]=xh;  v[3]=yh; v[4]=yl; v[5]=yh;
        v[6]=zh; v[7]=zl; v[8]=zh;  v[9]=sh; v[10]=sl; v[11]=one; v[12]=one;
        v[13]=0; v[14]=0; v[15]=0;
    }
#pragma unroll
    for (int k = 0; k < 16; ++k) vec[(size_t)i * 16 + k] = v[k];
}

// grid = (B_*RBLK, SPLITJ) = (256, 8). Block = 4 waves; wave w owns 64 rows
// (2 MFMA row-tiles); all waves sweep the same 1024-col j-chunk.
// A-frag: lane holds row (lane&31), k-half (lane>>5)*8. B-frag: col (lane&31).
__global__ __launch_bounds__(256)
void cham_mfma(const short8* __restrict__ Av,   // [BN*2] 16B halves per point
               const short8* __restrict__ Bv,   // [BN*2]
               uint* __restrict__ enc) {        // [2][BN] encoded mins
    __shared__ float cm[4][JCH];                // 16 KB per-wave colmins

    const int tid  = threadIdx.x;
    const int wave = tid >> 6;
    const int lane = tid & 63;
    const int half = lane >> 5;
    const int lc   = lane & 31;

    const int b    = blockIdx.x / RBLK;
    const int rb   = blockIdx.x % RBLK;
    const int row0 = rb * RPB + wave * 64;      // in-batch base row
    const int j0   = blockIdx.y * JCH;

    short8 a0 = Av[((size_t)b * N_ + row0 +      lc) * 2 + half];
    short8 a1 = Av[((size_t)b * N_ + row0 + 32 + lc) * 2 + half];

    f32x16 zc;
#pragma unroll
    for (int k = 0; k < 16; ++k) zc[k] = 0.0f;

    f32x16 rm0, rm1;
#pragma unroll
    for (int k = 0; k < 16; ++k) { rm0[k] = 3.0e38f; rm1[k] = 3.0e38f; }

    const short8* bp = Bv + ((size_t)b * M_ + j0 + lc) * 2 + half;

    for (int t = 0; t < JT; ++t) {
        short8 bfr = bp[t * 64];                // 32 cols * 2 halves
        f32x16 d0 = __builtin_amdgcn_mfma_f32_32x32x16_bf16(a0, bfr, zc, 0, 0, 0);
        f32x16 d1 = __builtin_amdgcn_mfma_f32_32x32x16_bf16(a1, bfr, zc, 0, 0, 0);
        float c0 = 3.0e38f;
#pragma unroll
        for (int k = 0; k < 16; ++k) {
            rm0[k] = fminf(rm0[k], d0[k]);
            rm1[k] = fminf(rm1[k], d1[k]);
            c0 = fminf(c0, fminf(d0[k], d1[k]));
        }
        c0 = fminf(c0, __shfl_xor(c0, 32));     // combine row-halves
        if (half == 0) cm[wave][t * 32 + lc] = c0;
    }

    // dist1 finalize: butterfly min across the 32 lanes of each half-group.
    // C layout: col=lane&31, row=(reg&3)+8*(reg>>2)+4*(lane>>5).
    uint* e1 = enc + (size_t)b * N_;
#pragma unroll
    for (int k = 0; k < 16; ++k) {
        float v0 = rm0[k], v1 = rm1[k];
#pragma unroll
        for (int s2 = 1; s2 < 32; s2 <<= 1) {
            v0 = fminf(v0, __shfl_xor(v0, s2));
            v1 = fminf(v1, __shfl_xor(v1, s2));
        }
        if (lc == 0) {
            int rr = (k & 3) + 8 * (k >> 2) + 4 * half;
            atomicMin(&e1[row0 + rr],      key_of(v0));
            atomicMin(&e1[row0 + 32 + rr], key_of(v1));
        }
    }

    __syncthreads();
    // dist2: combine 4 waves' per-col mins, one atomic per col per block.
    uint* e2 = enc + BN + (size_t)b * M_;
    for (int jj = tid; jj < JCH; jj += 256) {
        float m = fminf(fminf(cm[0][jj], cm[1][jj]),
                        fminf(cm[2][jj], cm[3][jj]));
        atomicMin(&e2[j0 + jj], key_of(m));
    }
}

__global__ void decode_kernel(const uint* __restrict__ enc,
                              float* __restrict__ out) {
    int i = blockIdx.x * blockDim.x + threadIdx.x;
    if (i < 2 * BN) out[i] = val_of(enc[i]);
}

extern "C" void kernel_launch(void* const* d_in, const int* in_sizes, int n_in,
                              void* d_out, int out_size, void* d_ws, size_t ws_size,
                              hipStream_t stream) {
    const float* xyz1 = (const float*)d_in[0];
    const float* xyz2 = (const float*)d_in[1];
    float* out = (float*)d_out;

    // ws: Av (2MB) | Bv (2MB) | enc (512KB)
    ushort* Av = (ushort*)d_ws;
    ushort* Bv = Av + (size_t)BN * 16;
    uint*  enc = (uint*)(Bv + (size_t)BN * 16);

    prep_kernel<<<BN / 256, 256, 0, stream>>>(xyz1, Av, 0);
    prep_kernel<<<BN / 256, 256, 0, stream>>>(xyz2, Bv, 1);
    init_kernel<<<(2 * BN) / 256, 256, 0, stream>>>(enc);

    dim3 grid(B_ * RBLK, SPLITJ);   // (256, 8)
    cham_mfma<<<grid, 256, 0, stream>>>((const short8*)Av, (const short8*)Bv, enc);

    decode_kernel<<<(2 * BN) / 256, 256, 0, stream>>>(enc, out);
}

// Round 6
// 63.419 us; speedup vs baseline: 1.6375x; 1.6375x over previous
//
#include <hip/hip_runtime.h>

// Chamfer distance via MFMA, two-pass row-min, B=8, N=M=8192.
// D[i,j] = sq_i + sq_j - 2<pi,pj> as one K=16 bf16 dot (hi/lo split, fp32-class):
//   A row-form: [xh,xh,xl, yh,yh,yl, zh,zh,zl, 1,1, sh,sl, 0,0,0]   (built in-kernel)
//   B col-form: [Xh,Xl,Xh, Yh,Yl,Yh, Zh,Zl,Zh, Sh,Sl, 1,1, 0,0,0]  (-2 on coords, packed)
// Each direction: row-min only. rm[k] = min3(d0[k], d1[k], rm[k]) -> 0.5 VALU/elem.

typedef unsigned int uint;
typedef unsigned short ushort;
typedef __attribute__((ext_vector_type(8))) short short8;
typedef __attribute__((ext_vector_type(16))) float f32x16;

#define B_     8
#define N_     8192
#define M_     8192
#define BN     (B_ * N_)        // 65536
#define SPLITJ 4
#define JCH    (M_ / SPLITJ)    // 2048 cols per wave sweep
#define JT     (JCH / 32)       // 64 col-tiles
#define RPW    64               // rows per wave (2 A-frags)
#define WAVES  4
#define RPB    (RPW * WAVES)    // 256 rows per block
#define RBLK   (N_ / RPB)       // 32 row-blocks per batch

__device__ __forceinline__ uint key_of(float f) {
    uint u = __float_as_uint(f);
    return (u & 0x80000000u) ? ~u : (u | 0x80000000u);
}
__device__ __forceinline__ float val_of(uint k) {
    return __uint_as_float((k & 0x80000000u) ? (k & 0x7FFFFFFFu) : ~k);
}
__device__ __forceinline__ ushort f2bf(float f) {   // RNE f32->bf16
    uint u = __float_as_uint(f);
    return (ushort)((u + 0x7FFFu + ((u >> 16) & 1u)) >> 16);
}
__device__ __forceinline__ float bf2f(ushort h) {
    return __uint_as_float(((uint)h) << 16);
}

__global__ void init_kernel(uint* __restrict__ enc) {
    int i = blockIdx.x * blockDim.x + threadIdx.x;
    if (i < 2 * BN) enc[i] = 0xFFFFFFFFu;
}

// Col-form pack, coords scaled by -2, sq unscaled.
__global__ void prep_kernel(const float* __restrict__ xyz, ushort* __restrict__ vec) {
    int i = blockIdx.x * blockDim.x + threadIdx.x;
    if (i >= BN) return;
    float x = xyz[3 * i], y = xyz[3 * i + 1], z = xyz[3 * i + 2];
    float s = fmaf(x, x, fmaf(y, y, z * z));
    x *= -2.0f; y *= -2.0f; z *= -2.0f;
    ushort xh = f2bf(x), xl = f2bf(x - bf2f(xh));
    ushort yh = f2bf(y), yl = f2bf(y - bf2f(yh));
    ushort zh = f2bf(z), zl = f2bf(z - bf2f(zh));
    ushort sh = f2bf(s), sl = f2bf(s - bf2f(sh));
    const uint one = 0x3F80u;
    uint4* dst = (uint4*)(vec + (size_t)i * 16);
    dst[0] = make_uint4((uint)xh | ((uint)xl << 16), (uint)xh | ((uint)yh << 16),
                        (uint)yl | ((uint)yh << 16), (uint)zh | ((uint)zl << 16));
    dst[1] = make_uint4((uint)zh | ((uint)sh << 16), (uint)sl | (one << 16),
                        one, 0u);
}

// Build A row-frag for global row g, k-half h, from raw xyz.
__device__ __forceinline__ short8 build_a(const float* __restrict__ own, int g, int h) {
    float x = own[3 * g], y = own[3 * g + 1], z = own[3 * g + 2];
    float s = fmaf(x, x, fmaf(y, y, z * z));
    ushort xh = f2bf(x), xl = f2bf(x - bf2f(xh));
    ushort yh = f2bf(y), yl = f2bf(y - bf2f(yh));
    ushort zh = f2bf(z), zl = f2bf(z - bf2f(zh));
    ushort sh = f2bf(s), sl = f2bf(s - bf2f(sh));
    const ushort one = 0x3F80;
    short8 a;
    a[0] = (short)(h ? zl  : xh);
    a[1] = (short)(h ? one : xh);
    a[2] = (short)(h ? one : xl);
    a[3] = (short)(h ? sh  : yh);
    a[4] = (short)(h ? sl  : yh);
    a[5] = (short)(h ? 0   : yl);
    a[6] = (short)(h ? 0   : zh);
    a[7] = (short)(h ? 0   : zh);
    return a;
}

// grid = (B_*RBLK, SPLITJ, 2) = (256, 4, 2). 4 waves/block, 64 rows/wave.
__global__ __launch_bounds__(256, 5)
void cham_mfma2(const float* __restrict__ xyz1, const float* __restrict__ xyz2,
                const short8* __restrict__ Bv1,  // col-form pack of cloud1
                const short8* __restrict__ Bv2,  // col-form pack of cloud2
                uint* __restrict__ enc) {        // [2][BN]
    const int tid  = threadIdx.x;
    const int wave = tid >> 6;
    const int lane = tid & 63;
    const int half = lane >> 5;
    const int lc   = lane & 31;

    const int b   = blockIdx.x / RBLK;
    const int rb  = blockIdx.x % RBLK;
    const int dir = blockIdx.z;

    const float*  own = dir ? xyz2 : xyz1;   // rows from this cloud
    const short8* Bv  = dir ? Bv1  : Bv2;    // sweep the other cloud

    const int row0 = rb * RPB + wave * RPW;  // in-batch row base for this wave
    const int gr   = b * N_ + row0;          // global row base

    const short8 a0 = build_a(own, gr + lc, half);
    const short8 a1 = build_a(own, gr + 32 + lc, half);

    f32x16 zc;
#pragma unroll
    for (int k = 0; k < 16; ++k) zc[k] = 0.0f;
    f32x16 rm0 = zc + 3.0e38f, rm1 = zc + 3.0e38f;

    const short8* bp = Bv + ((size_t)b * M_ + (size_t)blockIdx.y * JCH + lc) * 2 + half;

#pragma unroll 2
    for (int t = 0; t < JT; t += 2) {
        short8 q0 = bp[t * 64];
        short8 q1 = bp[t * 64 + 64];
        f32x16 d00 = __builtin_amdgcn_mfma_f32_32x32x16_bf16(a0, q0, zc, 0, 0, 0);
        f32x16 d01 = __builtin_amdgcn_mfma_f32_32x32x16_bf16(a0, q1, zc, 0, 0, 0);
        f32x16 d10 = __builtin_amdgcn_mfma_f32_32x32x16_bf16(a1, q0, zc, 0, 0, 0);
        f32x16 d11 = __builtin_amdgcn_mfma_f32_32x32x16_bf16(a1, q1, zc, 0, 0, 0);
#pragma unroll
        for (int k = 0; k < 16; ++k) {
            rm0[k] = fminf(fminf(d00[k], d01[k]), rm0[k]);   // -> v_min3_f32
            rm1[k] = fminf(fminf(d10[k], d11[k]), rm1[k]);
        }
    }

    // Butterfly min across the 32 col-lanes of each half-group.
#pragma unroll
    for (int k = 0; k < 16; ++k) {
#pragma unroll
        for (int s2 = 16; s2 >= 1; s2 >>= 1) {
            rm0[k] = fminf(rm0[k], __shfl_xor(rm0[k], s2));
            rm1[k] = fminf(rm1[k], __shfl_xor(rm1[k], s2));
        }
    }

    // C layout: row = (k&3) + 8*(k>>2) + 4*half, col = lane&31.
    uint* e = enc + (size_t)dir * BN + gr;
    if (lc == 0) {
#pragma unroll
        for (int k = 0; k < 16; ++k) {
            int rr = (k & 3) + 8 * (k >> 2) + 4 * half;
            atomicMin(&e[rr],      key_of(rm0[k]));
            atomicMin(&e[32 + rr], key_of(rm1[k]));
        }
    }
}

__global__ void decode_kernel(const uint* __restrict__ enc, float* __restrict__ out) {
    int i = blockIdx.x * blockDim.x + threadIdx.x;
    if (i < 2 * BN) out[i] = val_of(enc[i]);
}

extern "C" void kernel_launch(void* const* d_in, const int* in_sizes, int n_in,
                              void* d_out, int out_size, void* d_ws, size_t ws_size,
                              hipStream_t stream) {
    const float* xyz1 = (const float*)d_in[0];
    const float* xyz2 = (const float*)d_in[1];
    float* out = (float*)d_out;

    // ws: Bv1 (2MB) | Bv2 (2MB) | enc (512KB)
    ushort* Bv1 = (ushort*)d_ws;
    ushort* Bv2 = Bv1 + (size_t)BN * 16;
    uint*   enc = (uint*)(Bv2 + (size_t)BN * 16);

    prep_kernel<<<BN / 256, 256, 0, stream>>>(xyz1, Bv1);
    prep_kernel<<<BN / 256, 256, 0, stream>>>(xyz2, Bv2);
    init_kernel<<<(2 * BN) / 256, 256, 0, stream>>>(enc);

    dim3 grid(B_ * RBLK, SPLITJ, 2);   // (256, 4, 2)
    cham_mfma2<<<grid, 256, 0, stream>>>(xyz1, xyz2,
                                         (const short8*)Bv1, (const short8*)Bv2, enc);

    decode_kernel<<<(2 * BN) / 256, 256, 0, stream>>>(enc, out);
}

// Round 8
// 54.847 us; speedup vs baseline: 1.8934x; 1.1563x over previous
//
#include <hip/hip_runtime.h>

// Chamfer distance via MFMA, two-pass row-min, B=8, N=M=8192.
// D[i,j] = sq_i + sq_j - 2<pi,pj> as one K=16 bf16 dot (hi/lo split, fp32-class):
//   A row-form: [xh,xh,xl, yh,yh,yl, zh,zh,zl, 1,1, sh,sl, 0,0,0]  (built in-kernel)
//   B col-form: [Xh,Xl,Xh, Yh,Yl,Yh, Zh,Zl,Zh, Sh,Sl, 1,1, 0,0,0]  (-2 on coords)
// Inner body is the R6-proven one (fminf chains; LLVM may fuse to v_min3).
// Source-split reductions keep <=32 MFMA dest regs live -> all-VGPR, no
// accvgpr copies (R6's hidden VALU tax). No atomics: unique rows per block,
// partials to part[dir][sj][row]; decode does the 4-way min.

typedef unsigned int uint;
typedef unsigned short ushort;
typedef __attribute__((ext_vector_type(8))) short short8;
typedef __attribute__((ext_vector_type(16))) float f32x16;

#define B_     8
#define N_     8192
#define M_     8192
#define BN     (B_ * N_)        // 65536
#define SPLITJ 4
#define JCH    (M_ / SPLITJ)    // 2048 cols per wave sweep
#define JT     (JCH / 32)       // 64 col-tiles
#define RPW    64               // rows per wave (2 A-frags)
#define WAVES  4
#define RPB    (RPW * WAVES)    // 256 rows per block
#define RBLK   (N_ / RPB)       // 32 row-blocks per batch

__device__ __forceinline__ ushort f2bf(float f) {   // RNE f32->bf16
    uint u = __float_as_uint(f);
    return (ushort)((u + 0x7FFFu + ((u >> 16) & 1u)) >> 16);
}
__device__ __forceinline__ float bf2f(ushort h) {
    return __uint_as_float(((uint)h) << 16);
}

// Col-form pack for both clouds in one launch (coords scaled by -2, sq unscaled).
// grid = (BN/256, 2)
__global__ void prep_kernel(const float* __restrict__ x1, const float* __restrict__ x2,
                            ushort* __restrict__ v1, ushort* __restrict__ v2) {
    int i = blockIdx.x * 256 + threadIdx.x;
    const float* __restrict__ xyz = blockIdx.y ? x2 : x1;
    ushort* __restrict__ vec = blockIdx.y ? v2 : v1;
    float x = xyz[3 * i], y = xyz[3 * i + 1], z = xyz[3 * i + 2];
    float s = fmaf(x, x, fmaf(y, y, z * z));
    x *= -2.0f; y *= -2.0f; z *= -2.0f;
    ushort xh = f2bf(x), xl = f2bf(x - bf2f(xh));
    ushort yh = f2bf(y), yl = f2bf(y - bf2f(yh));
    ushort zh = f2bf(z), zl = f2bf(z - bf2f(zh));
    ushort sh = f2bf(s), sl = f2bf(s - bf2f(sh));
    const uint one = 0x3F80u;
    uint4* dst = (uint4*)(vec + (size_t)i * 16);
    dst[0] = make_uint4((uint)xh | ((uint)xl << 16), (uint)xh | ((uint)yh << 16),
                        (uint)yl | ((uint)yh << 16), (uint)zh | ((uint)zl << 16));
    dst[1] = make_uint4((uint)zh | ((uint)sh << 16), (uint)sl | (one << 16),
                        one, 0u);
}

// Build A row-frag for global row g, k-half h, from raw xyz.
__device__ __forceinline__ short8 build_a(const float* __restrict__ own, int g, int h) {
    float x = own[3 * g], y = own[3 * g + 1], z = own[3 * g + 2];
    float s = fmaf(x, x, fmaf(y, y, z * z));
    ushort xh = f2bf(x), xl = f2bf(x - bf2f(xh));
    ushort yh = f2bf(y), yl = f2bf(y - bf2f(yh));
    ushort zh = f2bf(z), zl = f2bf(z - bf2f(zh));
    ushort sh = f2bf(s), sl = f2bf(s - bf2f(sh));
    const ushort one = 0x3F80;
    short8 a;
    a[0] = (short)(h ? zl  : xh);
    a[1] = (short)(h ? one : xh);
    a[2] = (short)(h ? one : xl);
    a[3] = (short)(h ? sh  : yh);
    a[4] = (short)(h ? sl  : yh);
    a[5] = (short)(h ? 0   : yl);
    a[6] = (short)(h ? 0   : zh);
    a[7] = (short)(h ? 0   : zh);
    return a;
}

// grid = (B_*RBLK, SPLITJ, 2) = (256, 4, 2). 4 waves/block, 64 rows/wave.
__global__ __launch_bounds__(256, 4)
void cham_mfma4(const float* __restrict__ xyz1, const float* __restrict__ xyz2,
                const short8* __restrict__ Bv1,  // col-form pack of cloud1
                const short8* __restrict__ Bv2,  // col-form pack of cloud2
                float* __restrict__ part) {      // [2][SPLITJ][BN]
    const int tid  = threadIdx.x;
    const int wave = tid >> 6;
    const int lane = tid & 63;
    const int half = lane >> 5;
    const int lc   = lane & 31;

    const int b   = blockIdx.x / RBLK;
    const int rb  = blockIdx.x % RBLK;
    const int dir = blockIdx.z;

    const float*  own = dir ? xyz2 : xyz1;   // rows from this cloud
    const short8* Bv  = dir ? Bv1  : Bv2;    // sweep the other cloud

    const int row0 = rb * RPB + wave * RPW;
    const int gr   = b * N_ + row0;

    const short8 a0 = build_a(own, gr + lc, half);
    const short8 a1 = build_a(own, gr + 32 + lc, half);

    f32x16 zc;
#pragma unroll
    for (int k = 0; k < 16; ++k) zc[k] = 0.0f;
    f32x16 rm0, rm1;
#pragma unroll
    for (int k = 0; k < 16; ++k) { rm0[k] = 3.0e38f; rm1[k] = 3.0e38f; }

    const short8* bp = Bv + ((size_t)b * M_ + (size_t)blockIdx.y * JCH + lc) * 2 + half;

#pragma unroll 2
    for (int t = 0; t < JT; t += 2) {
        short8 q0 = bp[t * 64];
        short8 q1 = bp[t * 64 + 64];
        f32x16 d00 = __builtin_amdgcn_mfma_f32_32x32x16_bf16(a0, q0, zc, 0, 0, 0);
        f32x16 d01 = __builtin_amdgcn_mfma_f32_32x32x16_bf16(a0, q1, zc, 0, 0, 0);
#pragma unroll
        for (int k = 0; k < 16; ++k)
            rm0[k] = fminf(fminf(d00[k], d01[k]), rm0[k]);   // min3-fusable
        f32x16 d10 = __builtin_amdgcn_mfma_f32_32x32x16_bf16(a1, q0, zc, 0, 0, 0);
        f32x16 d11 = __builtin_amdgcn_mfma_f32_32x32x16_bf16(a1, q1, zc, 0, 0, 0);
#pragma unroll
        for (int k = 0; k < 16; ++k)
            rm1[k] = fminf(fminf(d10[k], d11[k]), rm1[k]);
    }

    // Butterfly min across the 32 col-lanes of each half-group.
#pragma unroll
    for (int k = 0; k < 16; ++k) {
#pragma unroll
        for (int s2 = 16; s2 >= 1; s2 >>= 1) {
            rm0[k] = fminf(rm0[k], __shfl_xor(rm0[k], s2));
            rm1[k] = fminf(rm1[k], __shfl_xor(rm1[k], s2));
        }
    }

    // C layout: row = (k&3) + 8*(k>>2) + 4*half, col = lane&31.
    float* p = part + ((size_t)dir * SPLITJ + blockIdx.y) * BN + gr;
    if (lc == 0) {
#pragma unroll
        for (int k = 0; k < 16; ++k) {
            int rr = (k & 3) + 8 * (k >> 2) + 4 * half;
            p[rr]      = rm0[k];
            p[32 + rr] = rm1[k];
        }
    }
}

// 4-way min over j-splits. i in [0, 2*BN).
__global__ void decode_kernel(const float* __restrict__ part, float* __restrict__ out) {
    int i = blockIdx.x * 256 + threadIdx.x;
    int dir = i / BN;
    int ii  = i - dir * BN;
    const float* p = part + (size_t)dir * SPLITJ * BN + ii;
    out[i] = fminf(fminf(p[0], p[(size_t)BN]),
                   fminf(p[(size_t)2 * BN], p[(size_t)3 * BN]));
}

extern "C" void kernel_launch(void* const* d_in, const int* in_sizes, int n_in,
                              void* d_out, int out_size, void* d_ws, size_t ws_size,
                              hipStream_t stream) {
    const float* xyz1 = (const float*)d_in[0];
    const float* xyz2 = (const float*)d_in[1];
    float* out = (float*)d_out;

    // ws: Bv1 (2MB) | Bv2 (2MB) | part (2MB)
    ushort* Bv1 = (ushort*)d_ws;
    ushort* Bv2 = Bv1 + (size_t)BN * 16;
    float*  part = (float*)(Bv2 + (size_t)BN * 16);

    dim3 pgrid(BN / 256, 2);
    prep_kernel<<<pgrid, 256, 0, stream>>>(xyz1, xyz2, Bv1, Bv2);

    dim3 grid(B_ * RBLK, SPLITJ, 2);   // (256, 4, 2)
    cham_mfma4<<<grid, 256, 0, stream>>>(xyz1, xyz2,
                                         (const short8*)Bv1, (const short8*)Bv2, part);

    decode_kernel<<<(2 * BN) / 256, 256, 0, stream>>>(part, out);
}

// Round 9
// 54.488 us; speedup vs baseline: 1.9058x; 1.0066x over previous
//
#include <hip/hip_runtime.h>

// Chamfer distance via MFMA, two-pass row-min, B=8, N=M=8192.
// D[i,j] = sq_i + sq_j - 2<pi,pj> as one K=16 bf16 dot (hi/lo split, fp32-class):
//   A row-form: [xh,xh,xl, yh,yh,yl, zh,zh,zl, 1,1, sh,sl, 0,0,0]  (built in-kernel)
//   B col-form: [Xh,Xl,Xh, Yh,Yl,Yh, Zh,Zl,Zh, Sh,Sl, 1,1, 0,0,0]  (-2 on coords)
// R9 delta vs R8: explicit 2-tile-ahead register prefetch (named buffers qa/qb)
// so the 4 MFMA + 32 min ops cover the L2 latency of the next tile-pair's loads.
// Everything else identical to the R8-proven kernel.

typedef unsigned int uint;
typedef unsigned short ushort;
typedef __attribute__((ext_vector_type(8))) short short8;
typedef __attribute__((ext_vector_type(16))) float f32x16;

#define B_     8
#define N_     8192
#define M_     8192
#define BN     (B_ * N_)        // 65536
#define SPLITJ 4
#define JCH    (M_ / SPLITJ)    // 2048 cols per wave sweep
#define JT     (JCH / 32)       // 64 col-tiles
#define RPW    64               // rows per wave (2 A-frags)
#define WAVES  4
#define RPB    (RPW * WAVES)    // 256 rows per block
#define RBLK   (N_ / RPB)       // 32 row-blocks per batch

__device__ __forceinline__ ushort f2bf(float f) {   // RNE f32->bf16
    uint u = __float_as_uint(f);
    return (ushort)((u + 0x7FFFu + ((u >> 16) & 1u)) >> 16);
}
__device__ __forceinline__ float bf2f(ushort h) {
    return __uint_as_float(((uint)h) << 16);
}

// Col-form pack for both clouds in one launch (coords scaled by -2, sq unscaled).
// grid = (BN/256, 2)
__global__ void prep_kernel(const float* __restrict__ x1, const float* __restrict__ x2,
                            ushort* __restrict__ v1, ushort* __restrict__ v2) {
    int i = blockIdx.x * 256 + threadIdx.x;
    const float* __restrict__ xyz = blockIdx.y ? x2 : x1;
    ushort* __restrict__ vec = blockIdx.y ? v2 : v1;
    float x = xyz[3 * i], y = xyz[3 * i + 1], z = xyz[3 * i + 2];
    float s = fmaf(x, x, fmaf(y, y, z * z));
    x *= -2.0f; y *= -2.0f; z *= -2.0f;
    ushort xh = f2bf(x), xl = f2bf(x - bf2f(xh));
    ushort yh = f2bf(y), yl = f2bf(y - bf2f(yh));
    ushort zh = f2bf(z), zl = f2bf(z - bf2f(zh));
    ushort sh = f2bf(s), sl = f2bf(s - bf2f(sh));
    const uint one = 0x3F80u;
    uint4* dst = (uint4*)(vec + (size_t)i * 16);
    dst[0] = make_uint4((uint)xh | ((uint)xl << 16), (uint)xh | ((uint)yh << 16),
                        (uint)yl | ((uint)yh << 16), (uint)zh | ((uint)zl << 16));
    dst[1] = make_uint4((uint)zh | ((uint)sh << 16), (uint)sl | (one << 16),
                        one, 0u);
}

// Build A row-frag for global row g, k-half h, from raw xyz.
__device__ __forceinline__ short8 build_a(const float* __restrict__ own, int g, int h) {
    float x = own[3 * g], y = own[3 * g + 1], z = own[3 * g + 2];
    float s = fmaf(x, x, fmaf(y, y, z * z));
    ushort xh = f2bf(x), xl = f2bf(x - bf2f(xh));
    ushort yh = f2bf(y), yl = f2bf(y - bf2f(yh));
    ushort zh = f2bf(z), zl = f2bf(z - bf2f(zh));
    ushort sh = f2bf(s), sl = f2bf(s - bf2f(sh));
    const ushort one = 0x3F80;
    short8 a;
    a[0] = (short)(h ? zl  : xh);
    a[1] = (short)(h ? one : xh);
    a[2] = (short)(h ? one : xl);
    a[3] = (short)(h ? sh  : yh);
    a[4] = (short)(h ? sl  : yh);
    a[5] = (short)(h ? 0   : yl);
    a[6] = (short)(h ? 0   : zh);
    a[7] = (short)(h ? 0   : zh);
    return a;
}

// grid = (B_*RBLK, SPLITJ, 2) = (256, 4, 2). 4 waves/block, 64 rows/wave.
__global__ __launch_bounds__(256, 4)
void cham_mfma5(const float* __restrict__ xyz1, const float* __restrict__ xyz2,
                const short8* __restrict__ Bv1,  // col-form pack of cloud1
                const short8* __restrict__ Bv2,  // col-form pack of cloud2
                float* __restrict__ part) {      // [2][SPLITJ][BN]
    const int tid  = threadIdx.x;
    const int wave = tid >> 6;
    const int lane = tid & 63;
    const int half = lane >> 5;
    const int lc   = lane & 31;

    const int b   = blockIdx.x / RBLK;
    const int rb  = blockIdx.x % RBLK;
    const int dir = blockIdx.z;

    const float*  own = dir ? xyz2 : xyz1;   // rows from this cloud
    const short8* Bv  = dir ? Bv1  : Bv2;    // sweep the other cloud

    const int row0 = rb * RPB + wave * RPW;
    const int gr   = b * N_ + row0;

    const short8 a0 = build_a(own, gr + lc, half);
    const short8 a1 = build_a(own, gr + 32 + lc, half);

    f32x16 zc;
#pragma unroll
    for (int k = 0; k < 16; ++k) zc[k] = 0.0f;
    f32x16 rm0, rm1;
#pragma unroll
    for (int k = 0; k < 16; ++k) { rm0[k] = 3.0e38f; rm1[k] = 3.0e38f; }

    const short8* bp = Bv + ((size_t)b * M_ + (size_t)blockIdx.y * JCH + lc) * 2 + half;

    // --- 2-tile-ahead register prefetch (named buffers, static indices) ---
    short8 qa0 = bp[0];
    short8 qa1 = bp[64];

    for (int t = 0; t < JT - 2; t += 2) {
        short8 qb0 = bp[(t + 2) * 64];          // issue next pair's loads first
        short8 qb1 = bp[(t + 3) * 64];
        f32x16 d00 = __builtin_amdgcn_mfma_f32_32x32x16_bf16(a0, qa0, zc, 0, 0, 0);
        f32x16 d01 = __builtin_amdgcn_mfma_f32_32x32x16_bf16(a0, qa1, zc, 0, 0, 0);
#pragma unroll
        for (int k = 0; k < 16; ++k)
            rm0[k] = fminf(fminf(d00[k], d01[k]), rm0[k]);   // min3-fusable
        f32x16 d10 = __builtin_amdgcn_mfma_f32_32x32x16_bf16(a1, qa0, zc, 0, 0, 0);
        f32x16 d11 = __builtin_amdgcn_mfma_f32_32x32x16_bf16(a1, qa1, zc, 0, 0, 0);
#pragma unroll
        for (int k = 0; k < 16; ++k)
            rm1[k] = fminf(fminf(d10[k], d11[k]), rm1[k]);
        qa0 = qb0;
        qa1 = qb1;
    }
    {   // last tile-pair (tiles JT-2, JT-1), already in qa0/qa1
        f32x16 d00 = __builtin_amdgcn_mfma_f32_32x32x16_bf16(a0, qa0, zc, 0, 0, 0);
        f32x16 d01 = __builtin_amdgcn_mfma_f32_32x32x16_bf16(a0, qa1, zc, 0, 0, 0);
#pragma unroll
        for (int k = 0; k < 16; ++k)
            rm0[k] = fminf(fminf(d00[k], d01[k]), rm0[k]);
        f32x16 d10 = __builtin_amdgcn_mfma_f32_32x32x16_bf16(a1, qa0, zc, 0, 0, 0);
        f32x16 d11 = __builtin_amdgcn_mfma_f32_32x32x16_bf16(a1, qa1, zc, 0, 0, 0);
#pragma unroll
        for (int k = 0; k < 16; ++k)
            rm1[k] = fminf(fminf(d10[k], d11[k]), rm1[k]);
    }

    // Butterfly min across the 32 col-lanes of each half-group.
#pragma unroll
    for (int k = 0; k < 16; ++k) {
#pragma unroll
        for (int s2 = 16; s2 >= 1; s2 >>= 1) {
            rm0[k] = fminf(rm0[k], __shfl_xor(rm0[k], s2));
            rm1[k] = fminf(rm1[k], __shfl_xor(rm1[k], s2));
        }
    }

    // C layout: row = (k&3) + 8*(k>>2) + 4*half, col = lane&31.
    float* p = part + ((size_t)dir * SPLITJ + blockIdx.y) * BN + gr;
    if (lc == 0) {
#pragma unroll
        for (int k = 0; k < 16; ++k) {
            int rr = (k & 3) + 8 * (k >> 2) + 4 * half;
            p[rr]      = rm0[k];
            p[32 + rr] = rm1[k];
        }
    }
}

// 4-way min over j-splits. i in [0, 2*BN).
__global__ void decode_kernel(const float* __restrict__ part, float* __restrict__ out) {
    int i = blockIdx.x * 256 + threadIdx.x;
    int dir = i / BN;
    int ii  = i - dir * BN;
    const float* p = part + (size_t)dir * SPLITJ * BN + ii;
    out[i] = fminf(fminf(p[0], p[(size_t)BN]),
                   fminf(p[(size_t)2 * BN], p[(size_t)3 * BN]));
}

extern "C" void kernel_launch(void* const* d_in, const int* in_sizes, int n_in,
                              void* d_out, int out_size, void* d_ws, size_t ws_size,
                              hipStream_t stream) {
    const float* xyz1 = (const float*)d_in[0];
    const float* xyz2 = (const float*)d_in[1];
    float* out = (float*)d_out;

    // ws: Bv1 (2MB) | Bv2 (2MB) | part (2MB)
    ushort* Bv1 = (ushort*)d_ws;
    ushort* Bv2 = Bv1 + (size_t)BN * 16;
    float*  part = (float*)(Bv2 + (size_t)BN * 16);

    dim3 pgrid(BN / 256, 2);
    prep_kernel<<<pgrid, 256, 0, stream>>>(xyz1, xyz2, Bv1, Bv2);

    dim3 grid(B_ * RBLK, SPLITJ, 2);   // (256, 4, 2)
    cham_mfma5<<<grid, 256, 0, stream>>>(xyz1, xyz2,
                                         (const short8*)Bv1, (const short8*)Bv2, part);

    decode_kernel<<<(2 * BN) / 256, 256, 0, stream>>>(part, out);
}